// Round 10
// baseline (269.127 us; speedup 1.0000x reference)
//
#include <hip/hip_runtime.h>
#include <math.h>

#define S_LEN 4096
#define HID   2048
#define NH    16
#define HD    128
#define NKV   2048
#define KT    64
#define QBLK  128
#define NT    (NKV / KT)
// (1/sqrt(128)) * log2(e) -- folded into Q so QK^T lands in exp2 domain
#define QSCALE 0.12754103668587426f

typedef __attribute__((ext_vector_type(8))) _Float16 half8;
typedef __attribute__((ext_vector_type(4))) _Float16 half4;
typedef __attribute__((ext_vector_type(2))) __fp16 fp16x2;
typedef __attribute__((ext_vector_type(4))) float f32x4;
typedef __attribute__((ext_vector_type(16))) float f32x16;

#define GLB_AS __attribute__((address_space(1)))
#define LDS_AS __attribute__((address_space(3)))

__device__ __forceinline__ void gload16(const void* g, void* l) {
  __builtin_amdgcn_global_load_lds((GLB_AS const void*)g, (LDS_AS void*)l, 16, 0, 0);
}

__device__ __forceinline__ unsigned pkrtz(float a, float b) {
  union { fp16x2 h; unsigned u; } cv;
  cv.h = __builtin_amdgcn_cvt_pkrtz(a, b);
  return cv.u;
}

// ---------- index build ----------
__global__ void k_build_idx(const int* __restrict__ hmap, int* __restrict__ gidx) {
  int i = blockIdx.x * 256 + threadIdx.x;
  if (i < NKV) gidx[i] = hmap[2 * i];
}

// ---------- fp32 -> fp16 conversion ----------
__global__ void k_cvt_f16(const float* __restrict__ src, _Float16* __restrict__ dst, int n8) {
  int i = blockIdx.x * 256 + threadIdx.x;
  if (i < n8) {
    float4 a = ((const float4*)src)[2 * i];
    float4 b = ((const float4*)src)[2 * i + 1];
    half8 h;
    h[0] = (_Float16)a.x; h[1] = (_Float16)a.y; h[2] = (_Float16)a.z; h[3] = (_Float16)a.w;
    h[4] = (_Float16)b.x; h[5] = (_Float16)b.y; h[6] = (_Float16)b.z; h[7] = (_Float16)b.w;
    ((half8*)dst)[i] = h;
  }
}

// ---------- fp16 MFMA NT GEMM, BK=64, swizzled LDS, staged-under-MFMA ----------
// MODE 0: f16 C; MODE 1: f32 C; MODE 2: write pre-swizzled K/Vt images (KV GEMM)
template<int MODE>
__global__ __launch_bounds__(256)
void k_gemm2(const _Float16* __restrict__ A, const _Float16* __restrict__ B,
             void* __restrict__ Cv, int M, int N, int K,
             const int* __restrict__ arow,
             char* __restrict__ kimg, char* __restrict__ vtimg)
{
  __shared__ __align__(16) char Asl[16384];
  __shared__ __align__(16) char Bsl[16384];
  const int tid = threadIdx.x;
  const int w = tid >> 6, lane = tid & 63;
  const int l15 = lane & 15, l4 = lane >> 4;
  const int m0 = blockIdx.y * 128, n0 = blockIdx.x * 128;
  const int wr = w >> 1, wc = w & 1;

  const int srow  = lane >> 3;
  const int kso   = ((lane & 7) ^ srow) * 8;   // f16 elements
  const _Float16* Ap[4];
  const _Float16* Bp[4];
#pragma unroll
  for (int q = 0; q < 4; ++q) {
    int arel = m0 + 32 * w + 8 * q + srow;
    int ra = arow ? arow[arel] : arel;
    Ap[q] = A + (size_t)ra * K + kso;
    Bp[q] = B + (size_t)(n0 + 32 * w + 8 * q + srow) * K + kso;
  }

  f32x4 acc[4][4];
#pragma unroll
  for (int i = 0; i < 4; ++i)
#pragma unroll
    for (int j = 0; j < 4; ++j) acc[i][j] = (f32x4){0.f, 0.f, 0.f, 0.f};

#define STAGE_T(k0)                                                  \
  do {                                                               \
    _Pragma("unroll")                                                \
    for (int q = 0; q < 4; ++q) {                                    \
      gload16(Ap[q] + (k0), Asl + (4 * w + q) * 1024 + lane * 16);   \
      gload16(Bp[q] + (k0), Bsl + (4 * w + q) * 1024 + lane * 16);   \
    }                                                                \
  } while (0)

  STAGE_T(0);
  __syncthreads();

  const int nt = K >> 6;
  for (int t = 0; t < nt; ++t) {
    half8 af[4][2], bf[4][2];
#pragma unroll
    for (int mi = 0; mi < 4; ++mi) {
      int row = wr * 64 + mi * 16 + l15;
#pragma unroll
      for (int ks = 0; ks < 2; ++ks)
        af[mi][ks] = *(const half8*)(Asl + row * 128 + (((ks * 4 + l4) ^ (row & 7)) * 16));
    }
#pragma unroll
    for (int ni = 0; ni < 4; ++ni) {
      int row = wc * 64 + ni * 16 + l15;
#pragma unroll
      for (int ks = 0; ks < 2; ++ks)
        bf[ni][ks] = *(const half8*)(Bsl + row * 128 + (((ks * 4 + l4) ^ (row & 7)) * 16));
    }
    __syncthreads();
    if (t + 1 < nt) STAGE_T((t + 1) * 64);
    __builtin_amdgcn_s_setprio(1);
#pragma unroll
    for (int mi = 0; mi < 4; ++mi)
#pragma unroll
      for (int ni = 0; ni < 4; ++ni)
#pragma unroll
        for (int ks = 0; ks < 2; ++ks)
          acc[mi][ni] = __builtin_amdgcn_mfma_f32_16x16x32_f16(af[mi][ks], bf[ni][ks], acc[mi][ni], 0, 0, 0);
    __builtin_amdgcn_s_setprio(0);
    __syncthreads();
  }
#undef STAGE_T

  const int rbase = m0 + wr * 64 + l4 * 4;
  const int cbase = n0 + wc * 64 + l15;
#pragma unroll
  for (int mi = 0; mi < 4; ++mi)
#pragma unroll
    for (int ni = 0; ni < 4; ++ni)
#pragma unroll
      for (int e = 0; e < 4; ++e) {
        int row = rbase + mi * 16 + e;
        int col = cbase + ni * 16;
        if (MODE == 1) {
          ((float*)Cv)[(size_t)row * N + col] = acc[mi][ni][e];
        } else if (MODE == 0) {
          ((_Float16*)Cv)[(size_t)row * N + col] = (_Float16)acc[mi][ni][e];
        } else {
          _Float16 val = (_Float16)acc[mi][ni][e];
          int t = row >> 6, j = row & 63;
          if (col < HID) {
            int h = col >> 7, d = col & 127;
            int off = (h * 32 + t) * 16384 + ((j * 256 + 2 * d) ^ ((j & 7) << 4));
            *(_Float16*)(kimg + off) = val;
          } else {
            int nn = col - HID;
            int h = nn >> 7, d = nn & 127;
            int off = (h * 32 + t) * 16384 + ((d * 128 + 2 * j) ^ ((d & 7) << 4));
            *(_Float16*)(vtimg + off) = val;
          }
        }
      }
}

// ---------- 32x32 MFMA flash attention: pair-split KV, no-max softmax ----------
// 512 threads = 8 waves = 4 pairs. Pair g owns 32 q rows (q=l31); within a pair,
// wave p=w&1 handles j-half [32p,32p+32) of each 64-j tile. exp2 with NO max
// subtraction (shift-invariance; s range-safe). Merge acc+l at end via LDS.
// grid 512 = 2 blocks/CU; LDS 66048 B/block.
__global__ __launch_bounds__(512, 4)
void k_attn6(const _Float16* __restrict__ qmat, const char* __restrict__ kimg,
             const char* __restrict__ vtimg, const int* __restrict__ hmap,
             _Float16* __restrict__ att)
{
  extern __shared__ __align__(16) char lds[];
  const int tid = threadIdx.x;
  const int w = tid >> 6, lane = tid & 63;
  const int l31 = lane & 31;
  const bool hi = (lane >> 5) != 0;
  const int hib = hi ? 1 : 0;
  const int g = w >> 1;      // q sub-block within QBLK
  const int p = w & 1;       // j-half
  const int work = (blockIdx.x & 7) * 64 + (blockIdx.x >> 3);  // XCD-chunked bijective
  const int h  = work >> 5;
  const int q0 = (work & 31) * QBLK;

  // Q fragments (B operand), prescaled by scale*log2e
  half8 qf[8];
  {
    const int qrow = q0 + g * 32 + l31;
    const _Float16* qb = qmat + (size_t)qrow * HID + h * HD + hib * 8;
    const _Float16 qs = (_Float16)QSCALE;
#pragma unroll
    for (int dk = 0; dk < 8; ++dk) {
      half8 v = *(const half8*)(qb + 16 * dk);
#pragma unroll
      for (int q = 0; q < 8; ++q) v[q] *= qs;
      qf[dk] = v;
    }
  }

  const char* kbase = kimg  + (size_t)h * NT * 16384;
  const char* vbase = vtimg + (size_t)h * NT * 16384;

  f32x16 acc[4];
#pragma unroll
  for (int dt = 0; dt < 4; ++dt)
#pragma unroll
    for (int r = 0; r < 16; ++r) acc[dt][r] = 0.f;
  float l = 0.f;

#define STAGE(buf, t)                                                          \
  do {                                                                         \
    const char* ks_ = kbase + (size_t)(t) * 16384;                             \
    const char* vs_ = vbase + (size_t)(t) * 16384;                             \
    char* d_ = lds + (buf) * 32768;                                            \
    gload16(ks_ + w * 1024 + lane * 16,          d_ + w * 1024);               \
    gload16(ks_ + (8 + w) * 1024 + lane * 16,    d_ + (8 + w) * 1024);         \
    gload16(vs_ + w * 1024 + lane * 16,          d_ + 16384 + w * 1024);       \
    gload16(vs_ + (8 + w) * 1024 + lane * 16,    d_ + 16384 + (8 + w) * 1024); \
  } while (0)

  STAGE(0, 0);
  asm volatile("s_waitcnt vmcnt(0)");
  __syncthreads();

  int cur = 0;
  for (int t = 0; t < NT; ++t) {
    if (t + 1 < NT) STAGE(cur ^ 1, t + 1);
    const char* kl = lds + cur * 32768;
    const char* vl = kl + 16384;

    // QK^T swapped (32x32), wave's j-half: A rows = K rows 32p..32p+31
    f32x16 s;
#pragma unroll
    for (int r = 0; r < 16; ++r) s[r] = 0.f;
    const int j = p * 32 + l31;
    __builtin_amdgcn_s_setprio(1);
#pragma unroll
    for (int dk = 0; dk < 8; ++dk) {
      half8 kf = *(const half8*)(kl + j * 256 + ((dk * 32 + hib * 16) ^ ((l31 & 7) << 4)));
      s = __builtin_amdgcn_mfma_f32_32x32x16_f16(kf, qf[dk], s, 0, 0, 0);
    }
    __builtin_amdgcn_s_setprio(0);

    // P = exp2(s) (no max: shift cancels in O/l); slice-wise pack + PV
    float psum = 0.f;
#pragma unroll
    for (int k1 = 0; k1 < 2; ++k1) {
      float pv[8];
#pragma unroll
      for (int r8 = 0; r8 < 8; ++r8) {
        pv[r8] = exp2f(s[8 * k1 + r8]);
        psum += pv[r8];
      }
      unsigned A0 = pkrtz(pv[0], pv[1]);
      unsigned A1 = pkrtz(pv[2], pv[3]);
      unsigned B0 = pkrtz(pv[4], pv[5]);
      unsigned B1 = pkrtz(pv[6], pv[7]);
      unsigned send0 = hi ? A0 : B0;
      unsigned send1 = hi ? A1 : B1;
      unsigned recv0 = (unsigned)__shfl_xor((int)send0, 32);
      unsigned recv1 = (unsigned)__shfl_xor((int)send1, 32);
      unsigned self0 = hi ? B0 : A0;
      unsigned self1 = hi ? B1 : A1;
      union { unsigned u[4]; half8 hv; } pf;
      pf.u[0] = hi ? recv0 : self0;
      pf.u[1] = hi ? recv1 : self1;
      pf.u[2] = hi ? self0 : recv0;
      pf.u[3] = hi ? self1 : recv1;
      const int ksa = 2 * p + k1;
      __builtin_amdgcn_s_setprio(1);
#pragma unroll
      for (int dt = 0; dt < 4; ++dt) {
        const int d = dt * 32 + l31;
        half8 vf = *(const half8*)(vl + d * 128 + ((ksa * 32 + hib * 16) ^ ((l31 & 7) << 4)));
        acc[dt] = __builtin_amdgcn_mfma_f32_32x32x16_f16(vf, pf.hv, acc[dt], 0, 0, 0);
      }
      __builtin_amdgcn_s_setprio(0);
    }
    psum += __shfl_xor(psum, 32);
    l += psum;

    asm volatile("s_waitcnt vmcnt(0)");
    __syncthreads();
    cur ^= 1;
  }
#undef STAGE

  // ---- pair merge through (now dead) K/V LDS buffers ----
  float* mrg = (float*)(lds + g * 16384);
  float* lsc = (float*)(lds + 65536 + g * 128);
  if (p) {
#pragma unroll
    for (int dt = 0; dt < 4; ++dt)
#pragma unroll
      for (int rq = 0; rq < 4; ++rq) {
        float4 v = {acc[dt][4 * rq + 0], acc[dt][4 * rq + 1],
                    acc[dt][4 * rq + 2], acc[dt][4 * rq + 3]};
        *(float4*)((char*)mrg + (dt * 4 + rq) * 1024 + lane * 16) = v;
      }
    if (!hi) lsc[l31] = l;
  }
  __syncthreads();
  if (!p) {
    const float lt = l + lsc[l31];
    const float rl = 1.0f / lt;
    const int qrow = q0 + g * 32 + l31;
    const int srow = hmap[qrow];
    _Float16* ob = att + (size_t)srow * HID + h * HD;
#pragma unroll
    for (int dt = 0; dt < 4; ++dt)
#pragma unroll
      for (int rq = 0; rq < 4; ++rq) {
        float4 o4 = *(const float4*)((char*)mrg + (dt * 4 + rq) * 1024 + lane * 16);
        const int d0 = dt * 32 + 8 * rq + 4 * hib;
        half4 o;
        o[0] = (_Float16)((acc[dt][4 * rq + 0] + o4.x) * rl);
        o[1] = (_Float16)((acc[dt][4 * rq + 1] + o4.y) * rl);
        o[2] = (_Float16)((acc[dt][4 * rq + 2] + o4.z) * rl);
        o[3] = (_Float16)((acc[dt][4 * rq + 3] + o4.w) * rl);
        *(half4*)(ob + d0) = o;
      }
  }
}

extern "C" void kernel_launch(void* const* d_in, const int* in_sizes, int n_in,
                              void* d_out, int out_size, void* d_ws, size_t ws_size,
                              hipStream_t stream)
{
  const float* x     = (const float*)d_in[0];
  const float* w_qkv = (const float*)d_in[1];
  const float* w_out = (const float*)d_in[2];
  const int*   hmap  = (const int*)d_in[3];
  float* out = (float*)d_out;

  char* ws = (char*)d_ws;
  int* gidx = (int*)ws;                                          ws += 8192;
  _Float16* x16    = (_Float16*)ws;  // aliased with att16 (x16 dead after GEMMs 1a/1b)
  _Float16* att16  = (_Float16*)ws;                              ws += (size_t)S_LEN * HID * 2;
  _Float16* wqkv16 = (_Float16*)ws;                              ws += (size_t)3 * HID * HID * 2;
  _Float16* wout16 = (_Float16*)ws;                              ws += (size_t)HID * HID * 2;
  _Float16* q16    = (_Float16*)ws;                              ws += (size_t)S_LEN * HID * 2;
  char* kimg  = ws;                                              ws += (size_t)NH * NT * 16384;
  char* vtimg = ws;

  k_build_idx<<<8, 256, 0, stream>>>(hmap, gidx);

  k_cvt_f16<<<(S_LEN * HID / 8 + 255) / 256, 256, 0, stream>>>(x, x16, S_LEN * HID / 8);
  k_cvt_f16<<<(3 * HID * HID / 8 + 255) / 256, 256, 0, stream>>>(w_qkv, wqkv16, 3 * HID * HID / 8);
  k_cvt_f16<<<(HID * HID / 8 + 255) / 256, 256, 0, stream>>>(w_out, wout16, HID * HID / 8);

  // Q = x @ wq^T  (4096 x 2048)
  dim3 gq(HID / 128, S_LEN / 128);
  k_gemm2<0><<<gq, 256, 0, stream>>>(x16, wqkv16, q16, S_LEN, HID, HID, nullptr, nullptr, nullptr);
  // KV = x[gidx] @ wkv^T  (2048 x 4096) -> written directly as swizzled K/Vt images
  dim3 gkv(2 * HID / 128, NKV / 128);
  k_gemm2<2><<<gkv, 256, 0, stream>>>(x16, wqkv16 + (size_t)HID * HID, nullptr,
                                      NKV, 2 * HID, HID, gidx, kimg, vtimg);

  k_attn6<<<NH * (S_LEN / QBLK), 512, 66048, stream>>>(q16, kimg, vtimg, hmap, att16);

  // out = att @ w_out^T  (4096 x 2048, fp32)
  dim3 go(HID / 128, S_LEN / 128);
  k_gemm2<1><<<go, 256, 0, stream>>>(att16, wout16, out, S_LEN, HID, HID, nullptr, nullptr, nullptr);
}

// Round 11
// 235.151 us; speedup vs baseline: 1.1445x; 1.1445x over previous
//
#include <hip/hip_runtime.h>
#include <math.h>

#define S_LEN 4096
#define HID   2048
#define NH    16
#define HD    128
#define NKV   2048
#define KT    64
#define QBLK  256
#define NT    (NKV / KT)
// (1/sqrt(128)) * log2(e) -- folded into Q so QK^T lands in exp2 domain
#define QSCALE 0.12754103668587426f

typedef __attribute__((ext_vector_type(8))) _Float16 half8;
typedef __attribute__((ext_vector_type(4))) _Float16 half4;
typedef __attribute__((ext_vector_type(2))) __fp16 fp16x2;
typedef __attribute__((ext_vector_type(4))) float f32x4;
typedef __attribute__((ext_vector_type(16))) float f32x16;

#define GLB_AS __attribute__((address_space(1)))
#define LDS_AS __attribute__((address_space(3)))

__device__ __forceinline__ void gload16(const void* g, void* l) {
  __builtin_amdgcn_global_load_lds((GLB_AS const void*)g, (LDS_AS void*)l, 16, 0, 0);
}

__device__ __forceinline__ unsigned pkrtz(float a, float b) {
  union { fp16x2 h; unsigned u; } cv;
  cv.h = __builtin_amdgcn_cvt_pkrtz(a, b);
  return cv.u;
}

// ---------- index build ----------
__global__ void k_build_idx(const int* __restrict__ hmap, int* __restrict__ gidx) {
  int i = blockIdx.x * 256 + threadIdx.x;
  if (i < NKV) gidx[i] = hmap[2 * i];
}

// ---------- fp32 -> fp16 conversion ----------
__global__ void k_cvt_f16(const float* __restrict__ src, _Float16* __restrict__ dst, int n8) {
  int i = blockIdx.x * 256 + threadIdx.x;
  if (i < n8) {
    float4 a = ((const float4*)src)[2 * i];
    float4 b = ((const float4*)src)[2 * i + 1];
    half8 h;
    h[0] = (_Float16)a.x; h[1] = (_Float16)a.y; h[2] = (_Float16)a.z; h[3] = (_Float16)a.w;
    h[4] = (_Float16)b.x; h[5] = (_Float16)b.y; h[6] = (_Float16)b.z; h[7] = (_Float16)b.w;
    ((half8*)dst)[i] = h;
  }
}

// ---------- fp16 MFMA NT GEMM, BK=64, swizzled LDS, staged-under-MFMA ----------
// MODE 0: f16 C; MODE 1: f32 C; MODE 2: write pre-swizzled K/Vt images (KV GEMM)
template<int MODE>
__global__ __launch_bounds__(256)
void k_gemm2(const _Float16* __restrict__ A, const _Float16* __restrict__ B,
             void* __restrict__ Cv, int M, int N, int K,
             const int* __restrict__ arow,
             char* __restrict__ kimg, char* __restrict__ vtimg)
{
  __shared__ __align__(16) char Asl[16384];
  __shared__ __align__(16) char Bsl[16384];
  const int tid = threadIdx.x;
  const int w = tid >> 6, lane = tid & 63;
  const int l15 = lane & 15, l4 = lane >> 4;
  const int m0 = blockIdx.y * 128, n0 = blockIdx.x * 128;
  const int wr = w >> 1, wc = w & 1;

  const int srow  = lane >> 3;
  const int kso   = ((lane & 7) ^ srow) * 8;   // f16 elements
  const _Float16* Ap[4];
  const _Float16* Bp[4];
#pragma unroll
  for (int q = 0; q < 4; ++q) {
    int arel = m0 + 32 * w + 8 * q + srow;
    int ra = arow ? arow[arel] : arel;
    Ap[q] = A + (size_t)ra * K + kso;
    Bp[q] = B + (size_t)(n0 + 32 * w + 8 * q + srow) * K + kso;
  }

  f32x4 acc[4][4];
#pragma unroll
  for (int i = 0; i < 4; ++i)
#pragma unroll
    for (int j = 0; j < 4; ++j) acc[i][j] = (f32x4){0.f, 0.f, 0.f, 0.f};

#define STAGE_T(k0)                                                  \
  do {                                                               \
    _Pragma("unroll")                                                \
    for (int q = 0; q < 4; ++q) {                                    \
      gload16(Ap[q] + (k0), Asl + (4 * w + q) * 1024 + lane * 16);   \
      gload16(Bp[q] + (k0), Bsl + (4 * w + q) * 1024 + lane * 16);   \
    }                                                                \
  } while (0)

  STAGE_T(0);
  __syncthreads();

  const int nt = K >> 6;
  for (int t = 0; t < nt; ++t) {
    half8 af[4][2], bf[4][2];
#pragma unroll
    for (int mi = 0; mi < 4; ++mi) {
      int row = wr * 64 + mi * 16 + l15;
#pragma unroll
      for (int ks = 0; ks < 2; ++ks)
        af[mi][ks] = *(const half8*)(Asl + row * 128 + (((ks * 4 + l4) ^ (row & 7)) * 16));
    }
#pragma unroll
    for (int ni = 0; ni < 4; ++ni) {
      int row = wc * 64 + ni * 16 + l15;
#pragma unroll
      for (int ks = 0; ks < 2; ++ks)
        bf[ni][ks] = *(const half8*)(Bsl + row * 128 + (((ks * 4 + l4) ^ (row & 7)) * 16));
    }
    __syncthreads();
    if (t + 1 < nt) STAGE_T((t + 1) * 64);
    __builtin_amdgcn_s_setprio(1);
#pragma unroll
    for (int mi = 0; mi < 4; ++mi)
#pragma unroll
      for (int ni = 0; ni < 4; ++ni)
#pragma unroll
        for (int ks = 0; ks < 2; ++ks)
          acc[mi][ni] = __builtin_amdgcn_mfma_f32_16x16x32_f16(af[mi][ks], bf[ni][ks], acc[mi][ni], 0, 0, 0);
    __builtin_amdgcn_s_setprio(0);
    __syncthreads();
  }
#undef STAGE_T

  const int rbase = m0 + wr * 64 + l4 * 4;
  const int cbase = n0 + wc * 64 + l15;
#pragma unroll
  for (int mi = 0; mi < 4; ++mi)
#pragma unroll
    for (int ni = 0; ni < 4; ++ni)
#pragma unroll
      for (int e = 0; e < 4; ++e) {
        int row = rbase + mi * 16 + e;
        int col = cbase + ni * 16;
        if (MODE == 1) {
          ((float*)Cv)[(size_t)row * N + col] = acc[mi][ni][e];
        } else if (MODE == 0) {
          ((_Float16*)Cv)[(size_t)row * N + col] = (_Float16)acc[mi][ni][e];
        } else {
          _Float16 val = (_Float16)acc[mi][ni][e];
          int t = row >> 6, j = row & 63;
          if (col < HID) {
            int h = col >> 7, d = col & 127;
            int off = (h * 32 + t) * 16384 + ((j * 256 + 2 * d) ^ ((j & 7) << 4));
            *(_Float16*)(kimg + off) = val;
          } else {
            int nn = col - HID;
            int h = nn >> 7, d = nn & 127;
            int off = (h * 32 + t) * 16384 + ((d * 128 + 2 * j) ^ ((d & 7) << 4));
            *(_Float16*)(vtimg + off) = val;
          }
        }
      }
}

// ---------- 32x32 MFMA flash attention: no-max softmax, hoisted LDS offsets ----------
// 512 threads = 8 waves; wave owns 32 q rows (q = l&31); KV tiles of 64.
// grid = 256 blocks (1/CU). LDS 2 x (K 16KB + Vt 16KB) = 64KB.
// Tile loop unrolled x2 so buffer index is compile-time -> all ds_reads are
// base-VGPR + 16-bit immediate (zero per-tile address VALU).
__global__ __launch_bounds__(512, 2)
void k_attn7(const _Float16* __restrict__ qmat, const char* __restrict__ kimg,
             const char* __restrict__ vtimg, const int* __restrict__ hmap,
             _Float16* __restrict__ att)
{
  extern __shared__ __align__(16) char lds[];
  const int tid = threadIdx.x;
  const int w = tid >> 6, lane = tid & 63;
  const int l31 = lane & 31;
  const bool hi = (lane >> 5) != 0;
  const int hib = hi ? 1 : 0;
  const int work = (blockIdx.x & 7) * 32 + (blockIdx.x >> 3);  // XCD-chunked, bijective
  const int h  = work >> 4;
  const int q0 = (work & 15) * QBLK;

  // Q fragments (B operand): qf[dk]: k-dim d = dk*16 + hib*8 + e, col q = l31; prescaled
  half8 qf[8];
  {
    const int qrow = q0 + w * 32 + l31;
    const _Float16* qb = qmat + (size_t)qrow * HID + h * HD + hib * 8;
    const _Float16 qs = (_Float16)QSCALE;
#pragma unroll
    for (int dk = 0; dk < 8; ++dk) {
      half8 v = *(const half8*)(qb + 16 * dk);
#pragma unroll
      for (int q = 0; q < 8; ++q) v[q] *= qs;
      qf[dk] = v;
    }
  }

  half8 ones;
#pragma unroll
  for (int q = 0; q < 8; ++q) ones[q] = (_Float16)1.0f;

  // loop-invariant per-lane LDS offsets
  const int swz = (l31 & 7) << 4;
  int koff[4], voff[4];
#pragma unroll
  for (int i = 0; i < 4; ++i) {
    koff[i] = l31 * 256 + ((i * 32 + hib * 16) ^ swz);
    voff[i] = 16384 + l31 * 128 + ((i * 32 + hib * 16) ^ swz);
  }

  const char* kbase = kimg  + (size_t)h * NT * 16384;
  const char* vbase = vtimg + (size_t)h * NT * 16384;

  f32x16 acc[4];
  f32x16 accl;
#pragma unroll
  for (int dt = 0; dt < 4; ++dt)
#pragma unroll
    for (int r = 0; r < 16; ++r) acc[dt][r] = 0.f;
#pragma unroll
  for (int r = 0; r < 16; ++r) accl[r] = 0.f;

#define STAGE(buf, t)                                                          \
  do {                                                                         \
    const char* ks_ = kbase + (size_t)(t) * 16384;                             \
    const char* vs_ = vbase + (size_t)(t) * 16384;                             \
    char* d_ = lds + (buf) * 32768;                                            \
    gload16(ks_ + w * 1024 + lane * 16,          d_ + w * 1024);               \
    gload16(ks_ + (8 + w) * 1024 + lane * 16,    d_ + (8 + w) * 1024);         \
    gload16(vs_ + w * 1024 + lane * 16,          d_ + 16384 + w * 1024);       \
    gload16(vs_ + (8 + w) * 1024 + lane * 16,    d_ + 16384 + (8 + w) * 1024); \
  } while (0)

// One KV tile: CUR is a compile-time buffer index (0/1) so every ds_read
// address is koff/voff VGPR + constant immediate.
#define TILE(CUR, T)                                                           \
  do {                                                                         \
    if ((T) + 1 < NT) STAGE((CUR) ^ 1, (T) + 1);                               \
    f32x16 s[2];                                                               \
    __builtin_amdgcn_s_setprio(1);                                             \
    _Pragma("unroll")                                                          \
    for (int jt = 0; jt < 2; ++jt) {                                           \
      f32x16 ss;                                                               \
      _Pragma("unroll")                                                        \
      for (int r = 0; r < 16; ++r) ss[r] = 0.f;                                \
      _Pragma("unroll")                                                        \
      for (int dk = 0; dk < 8; ++dk) {                                         \
        half8 kf = *(const half8*)(lds + koff[dk & 3] +                        \
                    ((CUR) * 32768 + jt * 8192 + (dk >> 2) * 128));            \
        ss = __builtin_amdgcn_mfma_f32_32x32x16_f16(kf, qf[dk], ss, 0, 0, 0);  \
      }                                                                        \
      s[jt] = ss;                                                              \
    }                                                                          \
    __builtin_amdgcn_s_setprio(0);                                             \
    unsigned P_pk[2][4][2];                                                    \
    _Pragma("unroll")                                                          \
    for (int jt = 0; jt < 2; ++jt)                                             \
      _Pragma("unroll")                                                        \
      for (int rq = 0; rq < 4; ++rq)                                           \
        _Pragma("unroll")                                                      \
        for (int h2 = 0; h2 < 2; ++h2) {                                       \
          float p0 = exp2f(s[jt][4 * rq + 2 * h2]);                            \
          float p1 = exp2f(s[jt][4 * rq + 2 * h2 + 1]);                        \
          P_pk[jt][rq][h2] = pkrtz(p0, p1);                                    \
        }                                                                      \
    _Pragma("unroll")                                                          \
    for (int ks = 0; ks < 4; ++ks) {                                           \
      const int jt = ks >> 1, k1 = ks & 1;                                     \
      unsigned send0 = hi ? P_pk[jt][2 * k1][0]     : P_pk[jt][2 * k1 + 1][0]; \
      unsigned send1 = hi ? P_pk[jt][2 * k1][1]     : P_pk[jt][2 * k1 + 1][1]; \
      unsigned recv0 = (unsigned)__shfl_xor((int)send0, 32);                   \
      unsigned recv1 = (unsigned)__shfl_xor((int)send1, 32);                   \
      unsigned self0 = hi ? P_pk[jt][2 * k1 + 1][0] : P_pk[jt][2 * k1][0];     \
      unsigned self1 = hi ? P_pk[jt][2 * k1 + 1][1] : P_pk[jt][2 * k1][1];     \
      union { unsigned u[4]; half8 hv; } pf;                                   \
      pf.u[0] = hi ? recv0 : self0;                                            \
      pf.u[1] = hi ? recv1 : self1;                                            \
      pf.u[2] = hi ? self0 : recv0;                                            \
      pf.u[3] = hi ? self1 : recv1;                                            \
      __builtin_amdgcn_s_setprio(1);                                           \
      _Pragma("unroll")                                                        \
      for (int dt = 0; dt < 4; ++dt) {                                         \
        half8 vf = *(const half8*)(lds + voff[ks] +                            \
                    ((CUR) * 32768 + dt * 4096));                              \
        acc[dt] = __builtin_amdgcn_mfma_f32_32x32x16_f16(vf, pf.hv, acc[dt], 0, 0, 0); \
      }                                                                        \
      accl = __builtin_amdgcn_mfma_f32_32x32x16_f16(ones, pf.hv, accl, 0, 0, 0); \
      __builtin_amdgcn_s_setprio(0);                                           \
    }                                                                          \
    asm volatile("s_waitcnt vmcnt(0)");                                        \
    __syncthreads();                                                           \
  } while (0)

  STAGE(0, 0);
  asm volatile("s_waitcnt vmcnt(0)");
  __syncthreads();

  for (int t = 0; t < NT; t += 2) {
    TILE(0, t);
    TILE(1, t + 1);
  }
#undef TILE
#undef STAGE

  // epilogue: lane owns O[d][q=l31], d = dt*32 + 8*rq + 4*hi + c; scatter by hmap
  const float rl = 1.0f / accl[0];
  const int qrow = q0 + w * 32 + l31;
  const int srow = hmap[qrow];
  _Float16* ob = att + (size_t)srow * HID + h * HD;
#pragma unroll
  for (int dt = 0; dt < 4; ++dt)
#pragma unroll
    for (int rq = 0; rq < 4; ++rq) {
      const int d0 = dt * 32 + 8 * rq + 4 * hib;
      half4 o;
      o[0] = (_Float16)(acc[dt][4 * rq + 0] * rl);
      o[1] = (_Float16)(acc[dt][4 * rq + 1] * rl);
      o[2] = (_Float16)(acc[dt][4 * rq + 2] * rl);
      o[3] = (_Float16)(acc[dt][4 * rq + 3] * rl);
      *(half4*)(ob + d0) = o;
    }
}

extern "C" void kernel_launch(void* const* d_in, const int* in_sizes, int n_in,
                              void* d_out, int out_size, void* d_ws, size_t ws_size,
                              hipStream_t stream)
{
  const float* x     = (const float*)d_in[0];
  const float* w_qkv = (const float*)d_in[1];
  const float* w_out = (const float*)d_in[2];
  const int*   hmap  = (const int*)d_in[3];
  float* out = (float*)d_out;

  char* ws = (char*)d_ws;
  int* gidx = (int*)ws;                                          ws += 8192;
  _Float16* x16    = (_Float16*)ws;  // aliased with att16 (x16 dead after GEMMs 1a/1b)
  _Float16* att16  = (_Float16*)ws;                              ws += (size_t)S_LEN * HID * 2;
  _Float16* wqkv16 = (_Float16*)ws;                              ws += (size_t)3 * HID * HID * 2;
  _Float16* wout16 = (_Float16*)ws;                              ws += (size_t)HID * HID * 2;
  _Float16* q16    = (_Float16*)ws;                              ws += (size_t)S_LEN * HID * 2;
  char* kimg  = ws;                                              ws += (size_t)NH * NT * 16384;
  char* vtimg = ws;

  k_build_idx<<<8, 256, 0, stream>>>(hmap, gidx);

  k_cvt_f16<<<(S_LEN * HID / 8 + 255) / 256, 256, 0, stream>>>(x, x16, S_LEN * HID / 8);
  k_cvt_f16<<<(3 * HID * HID / 8 + 255) / 256, 256, 0, stream>>>(w_qkv, wqkv16, 3 * HID * HID / 8);
  k_cvt_f16<<<(HID * HID / 8 + 255) / 256, 256, 0, stream>>>(w_out, wout16, HID * HID / 8);

  // Q = x @ wq^T  (4096 x 2048)
  dim3 gq(HID / 128, S_LEN / 128);
  k_gemm2<0><<<gq, 256, 0, stream>>>(x16, wqkv16, q16, S_LEN, HID, HID, nullptr, nullptr, nullptr);
  // KV = x[gidx] @ wkv^T  (2048 x 4096) -> written directly as swizzled K/Vt images
  dim3 gkv(2 * HID / 128, NKV / 128);
  k_gemm2<2><<<gkv, 256, 0, stream>>>(x16, wqkv16 + (size_t)HID * HID, nullptr,
                                      NKV, 2 * HID, HID, gidx, kimg, vtimg);

  k_attn7<<<NH * (S_LEN / QBLK), 512, 65536, stream>>>(q16, kimg, vtimg, hmap, att16);

  // out = att @ w_out^T  (4096 x 2048, fp32)
  dim3 go(HID / 128, S_LEN / 128);
  k_gemm2<1><<<go, 256, 0, stream>>>(att16, wout16, out, S_LEN, HID, HID, nullptr, nullptr, nullptr);
}